// Round 17
// baseline (168.497 us; speedup 1.0000x reference)
//
#include <hip/hip_runtime.h>

typedef unsigned int uint;
typedef unsigned short ushort;
typedef __attribute__((ext_vector_type(8))) short bf16x8;
typedef __attribute__((ext_vector_type(4))) float f32x4;

__device__ inline ushort f2bf(float f) {           // f32 -> bf16 RNE
    uint u = __float_as_uint(f);
    u += 0x7fff + ((u >> 16) & 1);
    return (ushort)(u >> 16);
}
__device__ inline uint pkbf(float lo, float hi) {  // 2xf32 -> packed bf16 pair (RNE)
    uint r;
    asm("v_cvt_pk_bf16_f32 %0, %1, %2" : "=v"(r) : "v"(lo), "v"(hi));
    return r;
}
__device__ inline float bflo(uint w) { return __uint_as_float(w << 16); }
__device__ inline float bfhi(uint w) { return __uint_as_float(w & 0xffff0000u); }

// ---- pack all weights into MFMA fragment order (bf16) ----------------------
// y 0..5: B-frags, generic: k = ks*32+(lane>>4)*8+e ; n = lane&15 ; t=k/CIN ci=k%CIN
// y == 6: dcn_off_w -> A-frags for SWAPPED offset conv (C^T = W·X)
// y == 7: dcn_w -> B-frags with phase-2 k-map:
//         tap = 2ks+(e>>2), dg = 2*(lane>>4)+((e>>1)&1), ci = dg*2+(e&1).
__global__ void packall_k(
    const float* __restrict__ fe_w1, const float* __restrict__ fe_w2,
    const float* __restrict__ fe_w3, const float* __restrict__ off_w0,
    const float* __restrict__ off_w1, const float* __restrict__ off_w2,
    const float* __restrict__ dcn_off_w, const float* __restrict__ dcn_w,
    ushort* __restrict__ pf1, ushort* __restrict__ pf2, ushort* __restrict__ pf3,
    ushort* __restrict__ po0, ushort* __restrict__ po1, ushort* __restrict__ po2,
    ushort* __restrict__ pow_, ushort* __restrict__ pd) {
    const int y = blockIdx.y;
    int i = blockIdx.x * 256 + threadIdx.x;
    int e = i & 7, lane = (i >> 3) & 63, rest = i >> 9;
    if (y == 6) {
        if (i >= 23040) return;
        int nt = rest % 9, ks = rest / 9;
        int m_idx = lane & 15;
        int ghat = m_idx >> 2, rhat = m_idx & 3;
        int c_orig = (2 * ghat + (rhat >> 1)) * 18 + nt * 2 + (rhat & 1);
        int k = ks * 32 + (lane >> 4) * 8 + e;
        int tapk = k >> 4, ci = k & 15;
        float v = (tapk < 9) ? dcn_off_w[(c_orig * 16 + ci) * 9 + tapk] : 0.f;
        pow_[i] = f2bf(v);
        return;
    }
    if (y == 7) {
        if (i >= 2560) return;
        int ks = rest;
        int co = lane & 15;
        int tap = 2 * ks + (e >> 2);
        int dg = 2 * (lane >> 4) + ((e >> 1) & 1);
        int ci = dg * 2 + (e & 1);
        float v = (tap < 9) ? dcn_w[(co * 16 + ci) * 9 + tap] : 0.f;
        pd[i] = f2bf(v);
        return;
    }
    const float* w; ushort* pk; int CIN, KS;
    switch (y) {
        case 0: w = fe_w1;  pk = pf1;  CIN = 16; KS = 5; break;
        case 1: w = fe_w2;  pk = pf2;  CIN = 16; KS = 5; break;
        case 2: w = fe_w3;  pk = pf3;  CIN = 16; KS = 5; break;
        case 3: w = off_w0; pk = po0;  CIN = 32; KS = 9; break;
        case 4: w = off_w1; pk = po1;  CIN = 32; KS = 9; break;
        default: w = off_w2; pk = po2; CIN = 32; KS = 9; break;
    }
    if (i >= KS * 512) return;
    int ks = rest;
    int k = ks * 32 + (lane >> 4) * 8 + e;
    int n = lane & 15;
    int t, ci;
    if (CIN == 16) { t = k >> 4; ci = k & 15; } else { t = k >> 5; ci = k & 31; }
    float v = (t < 9) ? w[(n * CIN + ci) * 9 + t] : 0.f;
    pk[i] = f2bf(v);
}

// ---------------- FE conv (CIN=16) on MFMA; both images via z ---------------
// output: cat buffer [pix][32] bf16 at channel offset img*16
template <bool PLANAR>
__launch_bounds__(256)
__global__ void fe_mfma_k(const float* __restrict__ pA, const float* __restrict__ pB,
                          const ushort* __restrict__ catin,
                          const ushort* __restrict__ pack, const float* __restrict__ bias,
                          ushort* __restrict__ catout,
                          int H, int W, int OH, int OW, int pad) {
    __shared__ ushort patch[324 * 16];               // [pos(18x18)][ci]
    const int tid = threadIdx.x;
    const int tx0 = blockIdx.x * 16, ty0 = blockIdx.y * 16;
    const int b = blockIdx.z & 3, img = blockIdx.z >> 2;
    const int bx = tx0 - pad, by = ty0 - pad;
    const int HW = H * W;

    if (PLANAR) {
        const float* inb = (img ? pB : pA) + (size_t)(b * 16) * HW;
        for (int pos = tid; pos < 324; pos += 256) {
            int r = pos / 18, c = pos - r * 18;
            int gy = by + r, gx = bx + c;
            bool ok = (unsigned)gy < (unsigned)H && (unsigned)gx < (unsigned)W;
            int base = gy * W + gx;
            uint o16[8];
#pragma unroll
            for (int ii = 0; ii < 8; ++ii) {
                float lo = ok ? inb[(2 * ii) * HW + base] : 0.f;
                float hi = ok ? inb[(2 * ii + 1) * HW + base] : 0.f;
                o16[ii] = (uint)f2bf(lo) | ((uint)f2bf(hi) << 16);
            }
            *(uint4*)(patch + pos * 16) = *(uint4*)&o16[0];
            *(uint4*)(patch + pos * 16 + 8) = *(uint4*)&o16[4];
        }
    } else {
        for (int c = tid; c < 648; c += 256) {
            int pos = c >> 1, h = c & 1;
            int r = pos / 18, col = pos - r * 18;
            int gy = by + r, gx = bx + col;
            uint4 v = make_uint4(0, 0, 0, 0);
            if ((unsigned)gy < (unsigned)H && (unsigned)gx < (unsigned)W)
                v = *(const uint4*)(catin + ((size_t)(b * H + gy) * W + gx) * 32 + img * 16 + h * 8);
            *(uint4*)(patch + pos * 16 + h * 8) = v;
        }
    }
    __syncthreads();

    const int lane = tid & 63, wv = tid >> 6;
    const int g = lane >> 4, ci0 = (g & 1) * 8, rowx = lane & 15;
    f32x4 acc[4];
    float bv = bias[rowx];
#pragma unroll
    for (int m = 0; m < 4; ++m) acc[m] = f32x4{bv, bv, bv, bv};

#pragma unroll
    for (int ks = 0; ks < 5; ++ks) {
        int t = 2 * ks + (g >> 1);
        int dy = t < 9 ? t / 3 : 0;
        int dx = t < 9 ? t - (t / 3) * 3 : 0;
        bf16x8 a[4];
#pragma unroll
        for (int m = 0; m < 4; ++m) {
            int r = wv * 4 + m + dy, cc = rowx + dx;
            a[m] = *(const bf16x8*)(patch + (r * 18 + cc) * 16 + ci0);
        }
        bf16x8 bfrag = *(const bf16x8*)((const uint4*)pack + ks * 64 + lane);
#pragma unroll
        for (int m = 0; m < 4; ++m)
            acc[m] = __builtin_amdgcn_mfma_f32_16x16x32_bf16(a[m], bfrag, acc[m], 0, 0, 0);
    }

    const int oxb = g * 4;
#pragma unroll
    for (int m = 0; m < 4; ++m) {
        int gy = ty0 + wv * 4 + m;
        if (gy >= OH) continue;
#pragma unroll
        for (int j = 0; j < 4; ++j) {
            int gx = tx0 + oxb + j;
            if (gx < OW)
                catout[((size_t)(b * OH + gy) * OW + gx) * 32 + img * 16 + rowx] =
                    f2bf(fmaxf(acc[m][j], 0.f));
        }
    }
}

// ---------------- offset-feature conv (CIN=32) on MFMA, 3 scales ------------
__launch_bounds__(256)
__global__ void off_mfma_k(const ushort* __restrict__ c0, const ushort* __restrict__ c1,
                           const ushort* __restrict__ c2,
                           const ushort* __restrict__ pk0, const ushort* __restrict__ pk1,
                           const ushort* __restrict__ pk2,
                           const float* __restrict__ b0, const float* __restrict__ b1,
                           const float* __restrict__ b2,
                           ushort* __restrict__ f0, ushort* __restrict__ f1,
                           ushort* __restrict__ f2) {
    const int z = blockIdx.z, s = z >> 2, b = z & 3;
    const int H = 192 - 2 * s, W = H;
    const ushort* cat  = s == 0 ? c0 : (s == 1 ? c1 : c2);
    const ushort* pack = s == 0 ? pk0 : (s == 1 ? pk1 : pk2);
    const float* bias  = s == 0 ? b0 : (s == 1 ? b1 : b2);
    ushort* out        = s == 0 ? f0 : (s == 1 ? f1 : f2);

    __shared__ ushort patch[324 * 32];               // 20.7 KB
    const int tid = threadIdx.x;
    const int tx0 = blockIdx.x * 16, ty0 = blockIdx.y * 16;
    const int bx = tx0 - 1, by = ty0 - 1;

    for (int c = tid; c < 1296; c += 256) {
        int pos = c >> 2, h = c & 3;
        int r = pos / 18, col = pos - r * 18;
        int gy = by + r, gx = bx + col;
        uint4 v = make_uint4(0, 0, 0, 0);
        if ((unsigned)gy < (unsigned)H && (unsigned)gx < (unsigned)W)
            v = *(const uint4*)(cat + ((size_t)(b * H + gy) * W + gx) * 32 + h * 8);
        *(uint4*)(patch + pos * 32 + h * 8) = v;
    }
    __syncthreads();

    const int lane = tid & 63, wv = tid >> 6;
    const int g = lane >> 4, ci0 = g * 8, rowx = lane & 15;
    f32x4 acc[4];
    float bv = bias[rowx];
#pragma unroll
    for (int m = 0; m < 4; ++m) acc[m] = f32x4{bv, bv, bv, bv};

#pragma unroll
    for (int ks = 0; ks < 9; ++ks) {                 // K = 9 taps x 32ci exactly
        int dy = ks / 3, dx = ks - (ks / 3) * 3;
        bf16x8 a[4];
#pragma unroll
        for (int m = 0; m < 4; ++m) {
            int r = wv * 4 + m + dy, cc = rowx + dx;
            a[m] = *(const bf16x8*)(patch + (r * 18 + cc) * 32 + ci0);
        }
        bf16x8 bfrag = *(const bf16x8*)((const uint4*)pack + ks * 64 + lane);
#pragma unroll
        for (int m = 0; m < 4; ++m)
            acc[m] = __builtin_amdgcn_mfma_f32_16x16x32_bf16(a[m], bfrag, acc[m], 0, 0, 0);
    }

    const int oxb = g * 4;
#pragma unroll
    for (int m = 0; m < 4; ++m) {
        int gy = ty0 + wv * 4 + m;
        if (gy >= H) continue;
#pragma unroll
        for (int j = 0; j < 4; ++j) {
            int gx = tx0 + oxb + j;
            if (gx < W)
                out[((size_t)(b * H + gy) * W + gx) * 16 + rowx] = f2bf(fmaxf(acc[m][j], 0.f));
        }
    }
}

// ---- FUSED: swapped offset conv (lane-local offsets) -> sample -> MFMA -----
// 512-thread / 8-wave blocks on a 16-wide x 32-tall tile (occupancy A/B:
// same per-lane code as r16's 4-wave version; 2 resident blocks => 16 waves/CU).
__launch_bounds__(512)
__global__ void dcn_fused_k(const ushort* __restrict__ c0, const ushort* __restrict__ c1,
                            const ushort* __restrict__ c2,
                            const ushort* __restrict__ fb0, const ushort* __restrict__ fb1,
                            const ushort* __restrict__ fb2,
                            const ushort* __restrict__ owPack, const float* __restrict__ ob,
                            const ushort* __restrict__ pd, const float* __restrict__ db,
                            float* __restrict__ o0, float* __restrict__ o1,
                            float* __restrict__ o2) {
    const int z = blockIdx.z;
    const int s = z >> 2, b = z & 3;
    const int H = 192 - 2 * s, W = H;
    const ushort* cat = s == 0 ? c0 : (s == 1 ? c1 : c2);
    const ushort* fb  = s == 0 ? fb0 : (s == 1 ? fb1 : fb2);
    float* out        = s == 0 ? o0 : (s == 1 ? o1 : o2);
    const int HW = H * W;
    const size_t pixb = (size_t)b * HW;

    __shared__ uint xtu[8 * 836];        // x tile (bf16 ch-pairs), 38 rows x 22 cols, 26.8 KB

    const int tid = threadIdx.x;
    const int tx0 = blockIdx.x * 16, ty0 = blockIdx.y * 32;

    // ---- stage x tile (halo 3, bf16 ch-pairs) ----
    {
        const int bx3 = tx0 - 3, by3 = ty0 - 3;
        for (int pos = tid; pos < 836; pos += 512) {
            int r = pos / 22, c = pos - r * 22;
            int gy2 = by3 + r, gx2 = bx3 + c;
            uint4 va = make_uint4(0, 0, 0, 0), vb = va;
            if ((unsigned)gy2 < (unsigned)H && (unsigned)gx2 < (unsigned)W) {
                const ushort* src = cat + (pixb + gy2 * W + gx2) * 32 + 16;
                va = *(const uint4*)src;
                vb = *(const uint4*)(src + 8);
            }
            xtu[0 * 836 + pos] = va.x; xtu[1 * 836 + pos] = va.y;
            xtu[2 * 836 + pos] = va.z; xtu[3 * 836 + pos] = va.w;
            xtu[4 * 836 + pos] = vb.x; xtu[5 * 836 + pos] = vb.y;
            xtu[6 * 836 + pos] = vb.z; xtu[7 * 836 + pos] = vb.w;
        }
    }
    __syncthreads();

    const int lane = tid & 63, wv = tid >> 6;     // wv 0..7
    const int g = lane >> 4, rowx = lane & 15;
    const int ci0 = (g & 1) * 8;
    const int px = tx0 + rowx;
    const float bv2 = db[rowx];

#pragma unroll 1
    for (int m = 0; m < 4; ++m) {
        const int py = ty0 + wv * 4 + m;

        // B-fragment loader (off_feat patch): tap 2ks+(g>>1), ci-half
        auto loadB = [&](int ks) -> uint4 {
            int t = 2 * ks + (g >> 1);
            int tc = t < 9 ? t : 0;
            int dy = tc / 3, dx = tc - (tc / 3) * 3;
            int gya = ty0 - 1 + wv * 4 + m + dy;
            int gxa = tx0 - 1 + rowx + dx;
            uint4 r = make_uint4(0, 0, 0, 0);
            if ((unsigned)gya < (unsigned)H && (unsigned)gxa < (unsigned)W)
                r = *(const uint4*)(fb + ((size_t)(b * H + gya) * W + gxa) * 16 + ci0);
            return r;
        };

        // ---- phase 1 (swapped): acc[n][r] = offset (tap=n, dg=2g+(r>>1), comp=r&1)
        f32x4 acc[9];
#pragma unroll
        for (int n = 0; n < 9; ++n) {
            f32x4 t;
#pragma unroll
            for (int r = 0; r < 4; ++r)
                t[r] = ob[(2 * g + (r >> 1)) * 18 + n * 2 + (r & 1)];
            acc[n] = t;
        }
        uint4 bvc = loadB(0);
#pragma unroll 1
        for (int ks = 0; ks < 5; ++ks) {
            uint4 bvn = make_uint4(0, 0, 0, 0);
            if (ks < 4) bvn = loadB(ks + 1);
            bf16x8 bfrag = *(bf16x8*)&bvc;
            const uint4* ap = (const uint4*)owPack + (size_t)(ks * 9) * 64 + lane;
#pragma unroll
            for (int n = 0; n < 9; ++n) {
                bf16x8 afrag = *(const bf16x8*)(ap + (size_t)n * 64);
                acc[n] = __builtin_amdgcn_mfma_f32_16x16x32_bf16(afrag, bfrag, acc[n], 0, 0, 0);
            }
            bvc = bvn;
        }

        // ---- phase 2: sample + deform-conv MFMA (offsets = static registers) ----
        f32x4 acc2 = f32x4{bv2, bv2, bv2, bv2};
#pragma unroll
        for (int ks = 0; ks < 5; ++ks) {
            uint a2[4];
#pragma unroll
            for (int u = 0; u < 4; ++u) {
                const int tap = 2 * ks + (u >> 1);
                if (tap < 9) {
                    const int dgA = 2 * g + (u & 1);
                    const int ky = tap / 3 - 1, kx = tap % 3 - 1;
                    float sy = (float)(py + ky) + acc[tap][(u & 1) * 2];
                    float sx = (float)(px + kx) + acc[tap][(u & 1) * 2 + 1];
                    float fy = floorf(sy), fx = floorf(sx);
                    int y0 = (int)fy, x0 = (int)fx;
                    float wy = sy - fy, wx = sx - fx;
                    float wy1 = 1.f - wy, wx1 = 1.f - wx;
                    float w00 = wy1 * wx1, w01 = wy1 * wx, w10 = wy * wx1, w11 = wy * wx;
                    int ly = y0 - (ty0 - 3), lx = x0 - (tx0 - 3);
                    float2 v00, v01, v10, v11;
                    if ((unsigned)ly <= 36u && (unsigned)lx <= 20u) {
                        const uint* tt = &xtu[dgA * 836 + ly * 22 + lx];
                        uint u00 = tt[0], u01 = tt[1], u10 = tt[22], u11 = tt[23];
                        v00 = make_float2(bflo(u00), bfhi(u00));
                        v01 = make_float2(bflo(u01), bfhi(u01));
                        v10 = make_float2(bflo(u10), bfhi(u10));
                        v11 = make_float2(bflo(u11), bfhi(u11));
                    } else {
                        v00 = v01 = v10 = v11 = make_float2(0.f, 0.f);
                        bool y0v = (unsigned)y0 < (unsigned)H;
                        bool y1v = (unsigned)(y0 + 1) < (unsigned)H;
                        bool x0v = (unsigned)x0 < (unsigned)W;
                        bool x1v = (unsigned)(x0 + 1) < (unsigned)W;
                        const ushort* cg = cat + (pixb + (size_t)y0 * W + x0) * 32 + 16 + 2 * dgA;
                        if (y0v && x0v) { uint uu = *(const uint*)cg;                 v00 = make_float2(bflo(uu), bfhi(uu)); }
                        if (y0v && x1v) { uint uu = *(const uint*)(cg + 32);          v01 = make_float2(bflo(uu), bfhi(uu)); }
                        if (y1v && x0v) { uint uu = *(const uint*)(cg + 32 * W);      v10 = make_float2(bflo(uu), bfhi(uu)); }
                        if (y1v && x1v) { uint uu = *(const uint*)(cg + 32 * W + 32); v11 = make_float2(bflo(uu), bfhi(uu)); }
                    }
                    float s0 = w00 * v00.x + w01 * v01.x + w10 * v10.x + w11 * v11.x;
                    float s1 = w00 * v00.y + w01 * v01.y + w10 * v10.y + w11 * v11.y;
                    a2[u] = pkbf(s0, s1);
                } else {
                    a2[u] = 0u;
                }
            }
            uint4 av = make_uint4(a2[0], a2[1], a2[2], a2[3]);
            bf16x8 af = *(bf16x8*)&av;
            bf16x8 dfrag = *(const bf16x8*)((const uint4*)pd + ks * 64 + lane);
            acc2 = __builtin_amdgcn_mfma_f32_16x16x32_bf16(af, dfrag, acc2, 0, 0, 0);
        }

        // ---- store row m: out channel = rowx, image col = g*4+j ----
        if (py < H) {
            float* op = out + (size_t)(b * 16 + rowx) * HW + (size_t)py * W;
#pragma unroll
            for (int j = 0; j < 4; ++j) {
                int gx2 = tx0 + g * 4 + j;
                if (gx2 < W) op[gx2] = acc2[j];
            }
        }
    }
}

// ---------------------------------------------------------------------------
extern "C" void kernel_launch(void* const* d_in, const int* in_sizes, int n_in,
                              void* d_out, int out_size, void* d_ws, size_t ws_size,
                              hipStream_t stream) {
    const float* ref_image = (const float*)d_in[0];
    const float* unreg_image = (const float*)d_in[1];
    const float* fe_w1 = (const float*)d_in[2];
    const float* fe_b1 = (const float*)d_in[3];
    const float* fe_w2 = (const float*)d_in[4];
    const float* fe_b2 = (const float*)d_in[5];
    const float* fe_w3 = (const float*)d_in[6];
    const float* fe_b3 = (const float*)d_in[7];
    const float* off_w0 = (const float*)d_in[8];
    const float* off_b0 = (const float*)d_in[9];
    const float* off_w1 = (const float*)d_in[10];
    const float* off_b1 = (const float*)d_in[11];
    const float* off_w2 = (const float*)d_in[12];
    const float* off_b2 = (const float*)d_in[13];
    const float* dcn_off_w = (const float*)d_in[14];
    const float* dcn_off_b = (const float*)d_in[15];
    const float* dcn_w = (const float*)d_in[16];
    const float* dcn_b = (const float*)d_in[17];

    const size_t pix[3] = {4ul * 192 * 192, 4ul * 190 * 190, 4ul * 188 * 188};
    const size_t szf[3] = {pix[0] * 16, pix[1] * 16, pix[2] * 16};

    size_t o = 0;
    auto take = [&](size_t bytes) {
        void* r = (char*)d_ws + o;
        o += (bytes + 255) & ~(size_t)255;
        return r;
    };
    ushort* cat[3]; ushort* fb[3];
    ushort* pf[3]; ushort* po[3]; ushort* owPack; ushort* pd;
    for (int s = 0; s < 3; ++s) cat[s] = (ushort*)take(pix[s] * 32 * 2);
    for (int s = 0; s < 3; ++s) fb[s] = (ushort*)take(pix[s] * 16 * 2);
    for (int s = 0; s < 3; ++s) pf[s] = (ushort*)take(2560 * 2);
    for (int s = 0; s < 3; ++s) po[s] = (ushort*)take(4608 * 2);
    owPack = (ushort*)take(23040 * 2);
    pd = (ushort*)take(2560 * 2);

    float* out0 = (float*)d_out;
    float* out1 = out0 + szf[0];
    float* out2 = out1 + szf[1];

    dim3 blk(256);

    packall_k<<<dim3(90, 8), blk, 0, stream>>>(
        fe_w1, fe_w2, fe_w3, off_w0, off_w1, off_w2, dcn_off_w, dcn_w,
        pf[0], pf[1], pf[2], po[0], po[1], po[2], owPack, pd);

    // FE convs (both images per launch), output -> cat buffers
    fe_mfma_k<true><<<dim3(12, 12, 8), blk, 0, stream>>>(
        ref_image, unreg_image, nullptr, pf[0], fe_b1, cat[0], 192, 192, 192, 192, 1);
    fe_mfma_k<false><<<dim3(12, 12, 8), blk, 0, stream>>>(
        nullptr, nullptr, cat[0], pf[1], fe_b2, cat[1], 192, 192, 190, 190, 0);
    fe_mfma_k<false><<<dim3(12, 12, 8), blk, 0, stream>>>(
        nullptr, nullptr, cat[1], pf[2], fe_b3, cat[2], 190, 190, 188, 188, 0);

    // offset-feature convs (all scales)
    off_mfma_k<<<dim3(12, 12, 12), blk, 0, stream>>>(
        cat[0], cat[1], cat[2], po[0], po[1], po[2],
        off_b0, off_b1, off_b2, fb[0], fb[1], fb[2]);

    // fused dcn-offset conv + deformable conv (all scales), 8-wave blocks
    dcn_fused_k<<<dim3(12, 6, 12), dim3(512), 0, stream>>>(
        cat[0], cat[1], cat[2], fb[0], fb[1], fb[2],
        owPack, dcn_off_b, pd, dcn_b, out0, out1, out2);
}

// Round 20
// 160.041 us; speedup vs baseline: 1.0528x; 1.0528x over previous
//
#include <hip/hip_runtime.h>

typedef unsigned int uint;
typedef unsigned short ushort;
typedef __attribute__((ext_vector_type(8))) short bf16x8;
typedef __attribute__((ext_vector_type(4))) float f32x4;

__device__ inline ushort f2bf(float f) {           // f32 -> bf16 RNE
    uint u = __float_as_uint(f);
    u += 0x7fff + ((u >> 16) & 1);
    return (ushort)(u >> 16);
}
__device__ inline uint pkbf(float lo, float hi) {  // 2xf32 -> packed bf16 pair (RNE)
    uint r;
    asm("v_cvt_pk_bf16_f32 %0, %1, %2" : "=v"(r) : "v"(lo), "v"(hi));
    return r;
}
__device__ inline float bflo(uint w) { return __uint_as_float(w << 16); }
__device__ inline float bfhi(uint w) { return __uint_as_float(w & 0xffff0000u); }

// ---- pack all weights into MFMA fragment order (bf16) ----------------------
// y 0..5: B-frags, generic: k = ks*32+(lane>>4)*8+e ; n = lane&15 ; t=k/CIN ci=k%CIN
// y == 6: dcn_off_w -> A-frags for SWAPPED offset conv (C^T = W·X)
// y == 7: dcn_w -> B-frags with phase-2 k-map:
//         tap = 2ks+(e>>2), dg = 2*(lane>>4)+((e>>1)&1), ci = dg*2+(e&1).
__global__ void packall_k(
    const float* __restrict__ fe_w1, const float* __restrict__ fe_w2,
    const float* __restrict__ fe_w3, const float* __restrict__ off_w0,
    const float* __restrict__ off_w1, const float* __restrict__ off_w2,
    const float* __restrict__ dcn_off_w, const float* __restrict__ dcn_w,
    ushort* __restrict__ pf1, ushort* __restrict__ pf2, ushort* __restrict__ pf3,
    ushort* __restrict__ po0, ushort* __restrict__ po1, ushort* __restrict__ po2,
    ushort* __restrict__ pow_, ushort* __restrict__ pd) {
    const int y = blockIdx.y;
    int i = blockIdx.x * 256 + threadIdx.x;
    int e = i & 7, lane = (i >> 3) & 63, rest = i >> 9;
    if (y == 6) {
        if (i >= 23040) return;
        int nt = rest % 9, ks = rest / 9;
        int m_idx = lane & 15;
        int ghat = m_idx >> 2, rhat = m_idx & 3;
        int c_orig = (2 * ghat + (rhat >> 1)) * 18 + nt * 2 + (rhat & 1);
        int k = ks * 32 + (lane >> 4) * 8 + e;
        int tapk = k >> 4, ci = k & 15;
        float v = (tapk < 9) ? dcn_off_w[(c_orig * 16 + ci) * 9 + tapk] : 0.f;
        pow_[i] = f2bf(v);
        return;
    }
    if (y == 7) {
        if (i >= 2560) return;
        int ks = rest;
        int co = lane & 15;
        int tap = 2 * ks + (e >> 2);
        int dg = 2 * (lane >> 4) + ((e >> 1) & 1);
        int ci = dg * 2 + (e & 1);
        float v = (tap < 9) ? dcn_w[(co * 16 + ci) * 9 + tap] : 0.f;
        pd[i] = f2bf(v);
        return;
    }
    const float* w; ushort* pk; int CIN, KS;
    switch (y) {
        case 0: w = fe_w1;  pk = pf1;  CIN = 16; KS = 5; break;
        case 1: w = fe_w2;  pk = pf2;  CIN = 16; KS = 5; break;
        case 2: w = fe_w3;  pk = pf3;  CIN = 16; KS = 5; break;
        case 3: w = off_w0; pk = po0;  CIN = 32; KS = 9; break;
        case 4: w = off_w1; pk = po1;  CIN = 32; KS = 9; break;
        default: w = off_w2; pk = po2; CIN = 32; KS = 9; break;
    }
    if (i >= KS * 512) return;
    int ks = rest;
    int k = ks * 32 + (lane >> 4) * 8 + e;
    int n = lane & 15;
    int t, ci;
    if (CIN == 16) { t = k >> 4; ci = k & 15; } else { t = k >> 5; ci = k & 31; }
    float v = (t < 9) ? w[(n * CIN + ci) * 9 + t] : 0.f;
    pk[i] = f2bf(v);
}

// ---------------- FE conv (CIN=16) on MFMA; both images via z ---------------
// output: cat buffer [pix][32] bf16 at channel offset img*16
template <bool PLANAR>
__launch_bounds__(256)
__global__ void fe_mfma_k(const float* __restrict__ pA, const float* __restrict__ pB,
                          const ushort* __restrict__ catin,
                          const ushort* __restrict__ pack, const float* __restrict__ bias,
                          ushort* __restrict__ catout,
                          int H, int W, int OH, int OW, int pad) {
    __shared__ ushort patch[324 * 16];               // [pos(18x18)][ci]
    const int tid = threadIdx.x;
    const int tx0 = blockIdx.x * 16, ty0 = blockIdx.y * 16;
    const int b = blockIdx.z & 3, img = blockIdx.z >> 2;
    const int bx = tx0 - pad, by = ty0 - pad;
    const int HW = H * W;

    if (PLANAR) {
        const float* inb = (img ? pB : pA) + (size_t)(b * 16) * HW;
        for (int pos = tid; pos < 324; pos += 256) {
            int r = pos / 18, c = pos - r * 18;
            int gy = by + r, gx = bx + c;
            bool ok = (unsigned)gy < (unsigned)H && (unsigned)gx < (unsigned)W;
            int base = gy * W + gx;
            uint o16[8];
#pragma unroll
            for (int ii = 0; ii < 8; ++ii) {
                float lo = ok ? inb[(2 * ii) * HW + base] : 0.f;
                float hi = ok ? inb[(2 * ii + 1) * HW + base] : 0.f;
                o16[ii] = (uint)f2bf(lo) | ((uint)f2bf(hi) << 16);
            }
            *(uint4*)(patch + pos * 16) = *(uint4*)&o16[0];
            *(uint4*)(patch + pos * 16 + 8) = *(uint4*)&o16[4];
        }
    } else {
        for (int c = tid; c < 648; c += 256) {
            int pos = c >> 1, h = c & 1;
            int r = pos / 18, col = pos - r * 18;
            int gy = by + r, gx = bx + col;
            uint4 v = make_uint4(0, 0, 0, 0);
            if ((unsigned)gy < (unsigned)H && (unsigned)gx < (unsigned)W)
                v = *(const uint4*)(catin + ((size_t)(b * H + gy) * W + gx) * 32 + img * 16 + h * 8);
            *(uint4*)(patch + pos * 16 + h * 8) = v;
        }
    }
    __syncthreads();

    const int lane = tid & 63, wv = tid >> 6;
    const int g = lane >> 4, ci0 = (g & 1) * 8, rowx = lane & 15;
    f32x4 acc[4];
    float bv = bias[rowx];
#pragma unroll
    for (int m = 0; m < 4; ++m) acc[m] = f32x4{bv, bv, bv, bv};

#pragma unroll
    for (int ks = 0; ks < 5; ++ks) {
        int t = 2 * ks + (g >> 1);
        int dy = t < 9 ? t / 3 : 0;
        int dx = t < 9 ? t - (t / 3) * 3 : 0;
        bf16x8 a[4];
#pragma unroll
        for (int m = 0; m < 4; ++m) {
            int r = wv * 4 + m + dy, cc = rowx + dx;
            a[m] = *(const bf16x8*)(patch + (r * 18 + cc) * 16 + ci0);
        }
        bf16x8 bfrag = *(const bf16x8*)((const uint4*)pack + ks * 64 + lane);
#pragma unroll
        for (int m = 0; m < 4; ++m)
            acc[m] = __builtin_amdgcn_mfma_f32_16x16x32_bf16(a[m], bfrag, acc[m], 0, 0, 0);
    }

    const int oxb = g * 4;
#pragma unroll
    for (int m = 0; m < 4; ++m) {
        int gy = ty0 + wv * 4 + m;
        if (gy >= OH) continue;
#pragma unroll
        for (int j = 0; j < 4; ++j) {
            int gx = tx0 + oxb + j;
            if (gx < OW)
                catout[((size_t)(b * OH + gy) * OW + gx) * 32 + img * 16 + rowx] =
                    f2bf(fmaxf(acc[m][j], 0.f));
        }
    }
}

// ---------------- offset-feature conv (CIN=32) on MFMA, 3 scales ------------
__launch_bounds__(256)
__global__ void off_mfma_k(const ushort* __restrict__ c0, const ushort* __restrict__ c1,
                           const ushort* __restrict__ c2,
                           const ushort* __restrict__ pk0, const ushort* __restrict__ pk1,
                           const ushort* __restrict__ pk2,
                           const float* __restrict__ b0, const float* __restrict__ b1,
                           const float* __restrict__ b2,
                           ushort* __restrict__ f0, ushort* __restrict__ f1,
                           ushort* __restrict__ f2) {
    const int z = blockIdx.z, s = z >> 2, b = z & 3;
    const int H = 192 - 2 * s, W = H;
    const ushort* cat  = s == 0 ? c0 : (s == 1 ? c1 : c2);
    const ushort* pack = s == 0 ? pk0 : (s == 1 ? pk1 : pk2);
    const float* bias  = s == 0 ? b0 : (s == 1 ? b1 : b2);
    ushort* out        = s == 0 ? f0 : (s == 1 ? f1 : f2);

    __shared__ ushort patch[324 * 32];               // 20.7 KB
    const int tid = threadIdx.x;
    const int tx0 = blockIdx.x * 16, ty0 = blockIdx.y * 16;
    const int bx = tx0 - 1, by = ty0 - 1;

    for (int c = tid; c < 1296; c += 256) {
        int pos = c >> 2, h = c & 3;
        int r = pos / 18, col = pos - r * 18;
        int gy = by + r, gx = bx + col;
        uint4 v = make_uint4(0, 0, 0, 0);
        if ((unsigned)gy < (unsigned)H && (unsigned)gx < (unsigned)W)
            v = *(const uint4*)(cat + ((size_t)(b * H + gy) * W + gx) * 32 + h * 8);
        *(uint4*)(patch + pos * 32 + h * 8) = v;
    }
    __syncthreads();

    const int lane = tid & 63, wv = tid >> 6;
    const int g = lane >> 4, ci0 = g * 8, rowx = lane & 15;
    f32x4 acc[4];
    float bv = bias[rowx];
#pragma unroll
    for (int m = 0; m < 4; ++m) acc[m] = f32x4{bv, bv, bv, bv};

#pragma unroll
    for (int ks = 0; ks < 9; ++ks) {                 // K = 9 taps x 32ci exactly
        int dy = ks / 3, dx = ks - (ks / 3) * 3;
        bf16x8 a[4];
#pragma unroll
        for (int m = 0; m < 4; ++m) {
            int r = wv * 4 + m + dy, cc = rowx + dx;
            a[m] = *(const bf16x8*)(patch + (r * 18 + cc) * 32 + ci0);
        }
        bf16x8 bfrag = *(const bf16x8*)((const uint4*)pack + ks * 64 + lane);
#pragma unroll
        for (int m = 0; m < 4; ++m)
            acc[m] = __builtin_amdgcn_mfma_f32_16x16x32_bf16(a[m], bfrag, acc[m], 0, 0, 0);
    }

    const int oxb = g * 4;
#pragma unroll
    for (int m = 0; m < 4; ++m) {
        int gy = ty0 + wv * 4 + m;
        if (gy >= H) continue;
#pragma unroll
        for (int j = 0; j < 4; ++j) {
            int gx = tx0 + oxb + j;
            if (gx < W)
                out[((size_t)(b * H + gy) * W + gx) * 16 + rowx] = f2bf(fmaxf(acc[m][j], 0.f));
        }
    }
}

// ---- FUSED: swapped offset conv (C^T, offsets land lane-local) -> sample ---
// Phase 1 computes D[ch][pix] = W·X so lane (g,rowx) holds, for ITS pixel
// rowx, offsets (tap=n, dg=2g+(reg>>1), comp=reg&1) in acc[n][reg]. Phase 2's
// k-order (baked into pd) assigns lane the samples (tap=2ks+(u>>1),
// dg=2g+(u&1)) -> all offsets are statically-indexed registers. No LDS
// repack, no ot buffer, offsets stay f32.
// NOTE: r18/r19's "polish" (lerp-form bilinear / uint2 corner loads) both
// produced NaN; this is the byte-exact r16 kernel (160.2 us, passed).
__launch_bounds__(256)
__global__ void dcn_fused_k(const ushort* __restrict__ c0, const ushort* __restrict__ c1,
                            const ushort* __restrict__ c2,
                            const ushort* __restrict__ fb0, const ushort* __restrict__ fb1,
                            const ushort* __restrict__ fb2,
                            const ushort* __restrict__ owPack, const float* __restrict__ ob,
                            const ushort* __restrict__ pd, const float* __restrict__ db,
                            float* __restrict__ o0, float* __restrict__ o1,
                            float* __restrict__ o2) {
    const int z = blockIdx.z;
    const int s = z >> 2, b = z & 3;
    const int H = 192 - 2 * s, W = H;
    const ushort* cat = s == 0 ? c0 : (s == 1 ? c1 : c2);
    const ushort* fb  = s == 0 ? fb0 : (s == 1 ? fb1 : fb2);
    float* out        = s == 0 ? o0 : (s == 1 ? o1 : o2);
    const int HW = H * W;
    const size_t pixb = (size_t)b * HW;

    __shared__ uint xtu[8 * 484];        // x tile (bf16 ch-pairs), halo 3, 15488 B

    const int tid = threadIdx.x;
    const int tx0 = blockIdx.x * 16, ty0 = blockIdx.y * 16;

    // ---- stage x tile (halo 3, bf16 ch-pairs) ----
    {
        const int bx3 = tx0 - 3, by3 = ty0 - 3;
        for (int pos = tid; pos < 484; pos += 256) {
            int r = pos / 22, c = pos - r * 22;
            int gy2 = by3 + r, gx2 = bx3 + c;
            uint4 va = make_uint4(0, 0, 0, 0), vb = va;
            if ((unsigned)gy2 < (unsigned)H && (unsigned)gx2 < (unsigned)W) {
                const ushort* src = cat + (pixb + gy2 * W + gx2) * 32 + 16;
                va = *(const uint4*)src;
                vb = *(const uint4*)(src + 8);
            }
            xtu[0 * 484 + pos] = va.x; xtu[1 * 484 + pos] = va.y;
            xtu[2 * 484 + pos] = va.z; xtu[3 * 484 + pos] = va.w;
            xtu[4 * 484 + pos] = vb.x; xtu[5 * 484 + pos] = vb.y;
            xtu[6 * 484 + pos] = vb.z; xtu[7 * 484 + pos] = vb.w;
        }
    }
    __syncthreads();

    const int lane = tid & 63, wv = tid >> 6;
    const int g = lane >> 4, rowx = lane & 15;
    const int ci0 = (g & 1) * 8;
    const int px = tx0 + rowx;
    const float bv2 = db[rowx];

#pragma unroll 1
    for (int m = 0; m < 4; ++m) {
        const int py = ty0 + wv * 4 + m;

        // B-fragment loader (off_feat patch): tap 2ks+(g>>1), ci-half
        auto loadB = [&](int ks) -> uint4 {
            int t = 2 * ks + (g >> 1);
            int tc = t < 9 ? t : 0;
            int dy = tc / 3, dx = tc - (tc / 3) * 3;
            int gya = ty0 - 1 + wv * 4 + m + dy;
            int gxa = tx0 - 1 + rowx + dx;
            uint4 r = make_uint4(0, 0, 0, 0);
            if ((unsigned)gya < (unsigned)H && (unsigned)gxa < (unsigned)W)
                r = *(const uint4*)(fb + ((size_t)(b * H + gya) * W + gxa) * 16 + ci0);
            return r;
        };

        // ---- phase 1 (swapped): acc[n][r] = offset (tap=n, dg=2g+(r>>1), comp=r&1)
        f32x4 acc[9];
#pragma unroll
        for (int n = 0; n < 9; ++n) {
            f32x4 t;
#pragma unroll
            for (int r = 0; r < 4; ++r)
                t[r] = ob[(2 * g + (r >> 1)) * 18 + n * 2 + (r & 1)];
            acc[n] = t;
        }
        uint4 bvc = loadB(0);
#pragma unroll 1
        for (int ks = 0; ks < 5; ++ks) {
            uint4 bvn = make_uint4(0, 0, 0, 0);
            if (ks < 4) bvn = loadB(ks + 1);
            bf16x8 bfrag = *(bf16x8*)&bvc;
            const uint4* ap = (const uint4*)owPack + (size_t)(ks * 9) * 64 + lane;
#pragma unroll
            for (int n = 0; n < 9; ++n) {
                bf16x8 afrag = *(const bf16x8*)(ap + (size_t)n * 64);
                acc[n] = __builtin_amdgcn_mfma_f32_16x16x32_bf16(afrag, bfrag, acc[n], 0, 0, 0);
            }
            bvc = bvn;
        }

        // ---- phase 2: sample + deform-conv MFMA (ks fully unrolled; offsets
        //      are statically-indexed registers) ----
        f32x4 acc2 = f32x4{bv2, bv2, bv2, bv2};
#pragma unroll
        for (int ks = 0; ks < 5; ++ks) {
            uint a2[4];
#pragma unroll
            for (int u = 0; u < 4; ++u) {
                const int tap = 2 * ks + (u >> 1);
                if (tap < 9) {
                    const int dgA = 2 * g + (u & 1);
                    const int ky = tap / 3 - 1, kx = tap % 3 - 1;
                    float sy = (float)(py + ky) + acc[tap][(u & 1) * 2];
                    float sx = (float)(px + kx) + acc[tap][(u & 1) * 2 + 1];
                    float fy = floorf(sy), fx = floorf(sx);
                    int y0 = (int)fy, x0 = (int)fx;
                    float wy = sy - fy, wx = sx - fx;
                    float wy1 = 1.f - wy, wx1 = 1.f - wx;
                    float w00 = wy1 * wx1, w01 = wy1 * wx, w10 = wy * wx1, w11 = wy * wx;
                    int ly = y0 - (ty0 - 3), lx = x0 - (tx0 - 3);
                    float2 v00, v01, v10, v11;
                    if ((unsigned)ly <= 20u && (unsigned)lx <= 20u) {
                        const uint* tt = &xtu[dgA * 484 + ly * 22 + lx];
                        uint u00 = tt[0], u01 = tt[1], u10 = tt[22], u11 = tt[23];
                        v00 = make_float2(bflo(u00), bfhi(u00));
                        v01 = make_float2(bflo(u01), bfhi(u01));
                        v10 = make_float2(bflo(u10), bfhi(u10));
                        v11 = make_float2(bflo(u11), bfhi(u11));
                    } else {
                        v00 = v01 = v10 = v11 = make_float2(0.f, 0.f);
                        bool y0v = (unsigned)y0 < (unsigned)H;
                        bool y1v = (unsigned)(y0 + 1) < (unsigned)H;
                        bool x0v = (unsigned)x0 < (unsigned)W;
                        bool x1v = (unsigned)(x0 + 1) < (unsigned)W;
                        const ushort* cg = cat + (pixb + (size_t)y0 * W + x0) * 32 + 16 + 2 * dgA;
                        if (y0v && x0v) { uint uu = *(const uint*)cg;                 v00 = make_float2(bflo(uu), bfhi(uu)); }
                        if (y0v && x1v) { uint uu = *(const uint*)(cg + 32);          v01 = make_float2(bflo(uu), bfhi(uu)); }
                        if (y1v && x0v) { uint uu = *(const uint*)(cg + 32 * W);      v10 = make_float2(bflo(uu), bfhi(uu)); }
                        if (y1v && x1v) { uint uu = *(const uint*)(cg + 32 * W + 32); v11 = make_float2(bflo(uu), bfhi(uu)); }
                    }
                    float s0 = w00 * v00.x + w01 * v01.x + w10 * v10.x + w11 * v11.x;
                    float s1 = w00 * v00.y + w01 * v01.y + w10 * v10.y + w11 * v11.y;
                    a2[u] = pkbf(s0, s1);
                } else {
                    a2[u] = 0u;
                }
            }
            uint4 av = make_uint4(a2[0], a2[1], a2[2], a2[3]);
            bf16x8 af = *(bf16x8*)&av;
            bf16x8 dfrag = *(const bf16x8*)((const uint4*)pd + ks * 64 + lane);
            acc2 = __builtin_amdgcn_mfma_f32_16x16x32_bf16(af, dfrag, acc2, 0, 0, 0);
        }

        // ---- store row m: out channel = rowx, image col = g*4+j ----
        if (py < H) {
            float* op = out + (size_t)(b * 16 + rowx) * HW + (size_t)py * W;
#pragma unroll
            for (int j = 0; j < 4; ++j) {
                int gx2 = tx0 + g * 4 + j;
                if (gx2 < W) op[gx2] = acc2[j];
            }
        }
    }
}

// ---------------------------------------------------------------------------
extern "C" void kernel_launch(void* const* d_in, const int* in_sizes, int n_in,
                              void* d_out, int out_size, void* d_ws, size_t ws_size,
                              hipStream_t stream) {
    const float* ref_image = (const float*)d_in[0];
    const float* unreg_image = (const float*)d_in[1];
    const float* fe_w1 = (const float*)d_in[2];
    const float* fe_b1 = (const float*)d_in[3];
    const float* fe_w2 = (const float*)d_in[4];
    const float* fe_b2 = (const float*)d_in[5];
    const float* fe_w3 = (const float*)d_in[6];
    const float* fe_b3 = (const float*)d_in[7];
    const float* off_w0 = (const float*)d_in[8];
    const float* off_b0 = (const float*)d_in[9];
    const float* off_w1 = (const float*)d_in[10];
    const float* off_b1 = (const float*)d_in[11];
    const float* off_w2 = (const float*)d_in[12];
    const float* off_b2 = (const float*)d_in[13];
    const float* dcn_off_w = (const float*)d_in[14];
    const float* dcn_off_b = (const float*)d_in[15];
    const float* dcn_w = (const float*)d_in[16];
    const float* dcn_b = (const float*)d_in[17];

    const size_t pix[3] = {4ul * 192 * 192, 4ul * 190 * 190, 4ul * 188 * 188};
    const size_t szf[3] = {pix[0] * 16, pix[1] * 16, pix[2] * 16};

    size_t o = 0;
    auto take = [&](size_t bytes) {
        void* r = (char*)d_ws + o;
        o += (bytes + 255) & ~(size_t)255;
        return r;
    };
    ushort* cat[3]; ushort* fb[3];
    ushort* pf[3]; ushort* po[3]; ushort* owPack; ushort* pd;
    for (int s = 0; s < 3; ++s) cat[s] = (ushort*)take(pix[s] * 32 * 2);
    for (int s = 0; s < 3; ++s) fb[s] = (ushort*)take(pix[s] * 16 * 2);
    for (int s = 0; s < 3; ++s) pf[s] = (ushort*)take(2560 * 2);
    for (int s = 0; s < 3; ++s) po[s] = (ushort*)take(4608 * 2);
    owPack = (ushort*)take(23040 * 2);
    pd = (ushort*)take(2560 * 2);

    float* out0 = (float*)d_out;
    float* out1 = out0 + szf[0];
    float* out2 = out1 + szf[1];

    dim3 blk(256);

    packall_k<<<dim3(90, 8), blk, 0, stream>>>(
        fe_w1, fe_w2, fe_w3, off_w0, off_w1, off_w2, dcn_off_w, dcn_w,
        pf[0], pf[1], pf[2], po[0], po[1], po[2], owPack, pd);

    // FE convs (both images per launch), output -> cat buffers
    fe_mfma_k<true><<<dim3(12, 12, 8), blk, 0, stream>>>(
        ref_image, unreg_image, nullptr, pf[0], fe_b1, cat[0], 192, 192, 192, 192, 1);
    fe_mfma_k<false><<<dim3(12, 12, 8), blk, 0, stream>>>(
        nullptr, nullptr, cat[0], pf[1], fe_b2, cat[1], 192, 192, 190, 190, 0);
    fe_mfma_k<false><<<dim3(12, 12, 8), blk, 0, stream>>>(
        nullptr, nullptr, cat[1], pf[2], fe_b3, cat[2], 190, 190, 188, 188, 0);

    // offset-feature convs (all scales)
    off_mfma_k<<<dim3(12, 12, 12), blk, 0, stream>>>(
        cat[0], cat[1], cat[2], po[0], po[1], po[2],
        off_b0, off_b1, off_b2, fb[0], fb[1], fb[2]);

    // fused dcn-offset conv + deformable conv (all scales)
    dcn_fused_k<<<dim3(12, 12, 12), blk, 0, stream>>>(
        cat[0], cat[1], cat[2], fb[0], fb[1], fb[2],
        owPack, dcn_off_b, pd, dcn_b, out0, out1, out2);
}